// Round 1
// baseline (266.140 us; speedup 1.0000x reference)
//
#include <hip/hip_runtime.h>
#include <stdint.h>

#define NMEM 100000
#define DIM 256
#define BQ 1024
#define KSEL 1024
#define NB 8192
#define CAP 4096

// ---- workspace layout (bytes) ----
#define OFF_SCORES   0                        // NMEM * 8 (double)
#define OFF_FSUM     (NMEM * 8)               // DIM * 8
#define OFF_FSQ      (OFF_FSUM + DIM * 8)     // 8
#define OFF_MINKEY   (OFF_FSQ + 8)            // 8
#define OFF_MAXKEY   (OFF_MINKEY + 8)         // 8
#define OFF_CSCORE   (OFF_MAXKEY + 8)         // CAP * 8
#define OFF_HIST     (OFF_CSCORE + CAP * 8)   // NB * 4
#define OFF_CIDX     (OFF_HIST + NB * 4)      // CAP * 4
#define OFF_COUNTER  (OFF_CIDX + CAP * 4)     // 4
#define OFF_BCUT     (OFF_COUNTER + 4)        // 4
#define OFF_TOPIDX   (OFF_BCUT + 4)           // KSEL * 4
// total ~888 KB

#define NEG_HUGE (-1.0e300)

__device__ inline unsigned long long d2k(double d) {
    unsigned long long u = (unsigned long long)__double_as_longlong(d);
    return (u & 0x8000000000000000ull) ? ~u : (u | 0x8000000000000000ull);
}
__device__ inline double k2d(unsigned long long k) {
    unsigned long long u = (k & 0x8000000000000000ull) ? (k ^ 0x8000000000000000ull) : ~k;
    return __longlong_as_double((long long)u);
}
__device__ inline int bucket_of(double s, double vmin, double scale) {
    int b = (int)((s - vmin) * scale);
    if (b < 0) b = 0;
    if (b > NB - 1) b = NB - 1;
    return b;
}

// ---------------- kernels ----------------

__global__ __launch_bounds__(256) void k_init(char* ws) {
    int* hist = (int*)(ws + OFF_HIST);
    double* fsum = (double*)(ws + OFF_FSUM);
    int tid = blockIdx.x * blockDim.x + threadIdx.x;
    int stride = gridDim.x * blockDim.x;
    for (int i = tid; i < NB; i += stride) hist[i] = 0;
    if (tid < DIM) fsum[tid] = 0.0;
    if (tid == 0) {
        *(double*)(ws + OFF_FSQ) = 0.0;
        *(unsigned long long*)(ws + OFF_MINKEY) = ~0ull;
        *(unsigned long long*)(ws + OFF_MAXKEY) = 0ull;
        *(int*)(ws + OFF_COUNTER) = 0;
        *(int*)(ws + OFF_BCUT) = 0;
    }
}

// features [BQ, DIM] -> f_sum[DIM] (double), f_sq (double)
__global__ __launch_bounds__(256) void k_fsum(const float* __restrict__ feat, char* ws) {
    double* fsum = (double*)(ws + OFF_FSUM);
    double* fsq  = (double*)(ws + OFF_FSQ);
    int d = threadIdx.x;          // 0..255 == column
    int r0 = blockIdx.x * 64;     // 16 blocks * 64 rows = 1024
    double s = 0.0, q = 0.0;
    for (int r = r0; r < r0 + 64; ++r) {
        double v = (double)feat[r * DIM + d];
        s += v;
        q += v * v;
    }
    atomicAdd(&fsum[d], s);
    __shared__ double red[256];
    red[d] = q;
    __syncthreads();
    for (int off = 128; off > 0; off >>= 1) {
        if (d < off) red[d] += red[d + off];
        __syncthreads();
    }
    if (d == 0) atomicAdd(fsq, red[0]);
}

// one wave (64 lanes) per memory row; 4 rows per 256-thread block
__global__ __launch_bounds__(256) void k_scores(const float* __restrict__ mem, char* ws) {
    const double* fsum = (const double*)(ws + OFF_FSUM);
    double* scores = (double*)(ws + OFF_SCORES);
    __shared__ double fs[DIM];
    int tid = threadIdx.x;
    fs[tid] = fsum[tid];
    __syncthreads();
    int wave = tid >> 6, lane = tid & 63;
    int row = blockIdx.x * 4 + wave;
    if (row < NMEM) {
        const float4* p = (const float4*)(mem + (size_t)row * DIM);
        float4 v = p[lane];
        const double* f = &fs[lane * 4];
        double msq  = (double)v.x * v.x + (double)v.y * v.y +
                      (double)v.z * v.z + (double)v.w * v.w;
        double cross = (double)v.x * f[0] + (double)v.y * f[1] +
                       (double)v.z * f[2] + (double)v.w * f[3];
        for (int off = 32; off > 0; off >>= 1) {
            msq   += __shfl_down(msq, off);
            cross += __shfl_down(cross, off);
        }
        if (lane == 0) {
            double fsq = *(const double*)(ws + OFF_FSQ);
            scores[row] = 2.0 * cross - (double)BQ * msq - fsq;
        }
    }
}

__global__ __launch_bounds__(256) void k_minmax(char* ws) {
    const double* scores = (const double*)(ws + OFF_SCORES);
    unsigned long long lmin = ~0ull, lmax = 0ull;
    int tid = blockIdx.x * blockDim.x + threadIdx.x;
    int stride = gridDim.x * blockDim.x;
    for (int i = tid; i < NMEM; i += stride) {
        unsigned long long k = d2k(scores[i]);
        if (k < lmin) lmin = k;
        if (k > lmax) lmax = k;
    }
    __shared__ unsigned long long smin[256], smax[256];
    int t = threadIdx.x;
    smin[t] = lmin; smax[t] = lmax;
    __syncthreads();
    for (int off = 128; off > 0; off >>= 1) {
        if (t < off) {
            if (smin[t + off] < smin[t]) smin[t] = smin[t + off];
            if (smax[t + off] > smax[t]) smax[t] = smax[t + off];
        }
        __syncthreads();
    }
    if (t == 0) {
        atomicMin((unsigned long long*)(ws + OFF_MINKEY), smin[0]);
        atomicMax((unsigned long long*)(ws + OFF_MAXKEY), smax[0]);
    }
}

__global__ __launch_bounds__(256) void k_hist(char* ws) {
    const double* scores = (const double*)(ws + OFF_SCORES);
    int* hist = (int*)(ws + OFF_HIST);
    double vmin = k2d(*(unsigned long long*)(ws + OFF_MINKEY));
    double vmax = k2d(*(unsigned long long*)(ws + OFF_MAXKEY));
    double scale = (vmax > vmin) ? (double)NB / (vmax - vmin) : 0.0;
    int tid = blockIdx.x * blockDim.x + threadIdx.x;
    int stride = gridDim.x * blockDim.x;
    for (int i = tid; i < NMEM; i += stride) {
        atomicAdd(&hist[bucket_of(scores[i], vmin, scale)], 1);
    }
}

// find largest b_cut s.t. count(bucket >= b_cut) >= KSEL
__global__ __launch_bounds__(1024) void k_scan(char* ws) {
    const int* hist = (const int*)(ws + OFF_HIST);
    __shared__ int h[NB];     // 32 KB
    __shared__ int suf[1024]; // 4 KB
    int t = threadIdx.x;
    for (int i = t; i < NB; i += 1024) h[i] = hist[i];
    __syncthreads();
    int cs = 0;
    for (int j = 0; j < 8; ++j) cs += h[t * 8 + j];
    suf[t] = cs;
    __syncthreads();
    for (int off = 1; off < 1024; off <<= 1) {
        int v = suf[t] + ((t + off < 1024) ? suf[t + off] : 0);
        __syncthreads();
        suf[t] = v;
        __syncthreads();
    }
    int nxt = (t < 1023) ? suf[t + 1] : 0;
    if (suf[t] >= KSEL && nxt < KSEL) {
        int cum = nxt;
        int bcut = t * 8;
        for (int b = t * 8 + 7; b >= t * 8; --b) {
            cum += h[b];
            if (cum >= KSEL) { bcut = b; break; }
        }
        *(int*)(ws + OFF_BCUT) = bcut;
    }
}

__global__ __launch_bounds__(256) void k_compact(char* ws) {
    const double* scores = (const double*)(ws + OFF_SCORES);
    double vmin = k2d(*(unsigned long long*)(ws + OFF_MINKEY));
    double vmax = k2d(*(unsigned long long*)(ws + OFF_MAXKEY));
    double scale = (vmax > vmin) ? (double)NB / (vmax - vmin) : 0.0;
    int bcut = *(const int*)(ws + OFF_BCUT);
    int* counter = (int*)(ws + OFF_COUNTER);
    double* cs = (double*)(ws + OFF_CSCORE);
    int* ci = (int*)(ws + OFF_CIDX);
    int tid = blockIdx.x * blockDim.x + threadIdx.x;
    int stride = gridDim.x * blockDim.x;
    for (int i = tid; i < NMEM; i += stride) {
        double s = scores[i];
        if (bucket_of(s, vmin, scale) >= bcut) {
            int p = atomicAdd(counter, 1);
            if (p < CAP) { cs[p] = s; ci[p] = i; }
        }
    }
}

// single-block bitonic sort of CAP elems: key = (-score, idx) ascending
__global__ __launch_bounds__(1024) void k_sort(char* ws) {
    int n = *(const int*)(ws + OFF_COUNTER);
    if (n > CAP) n = CAP;
    const double* cs = (const double*)(ws + OFF_CSCORE);
    const int* ci = (const int*)(ws + OFF_CIDX);
    __shared__ double s[CAP]; // 32 KB
    __shared__ int id[CAP];   // 16 KB
    int t = threadIdx.x;
    for (int i = t; i < CAP; i += 1024) {
        if (i < n) { s[i] = cs[i]; id[i] = ci[i]; }
        else       { s[i] = NEG_HUGE; id[i] = 0x7fffffff; }
    }
    for (int k = 2; k <= CAP; k <<= 1) {
        for (int j = k >> 1; j > 0; j >>= 1) {
            __syncthreads();
            for (int i = t; i < CAP; i += 1024) {
                int ixj = i ^ j;
                if (ixj > i) {
                    double si = s[i], sj = s[ixj];
                    int ii = id[i], ij = id[ixj];
                    // "greater" in ascending key (-score, idx) order
                    bool g = (si < sj) || (si == sj && ii > ij);
                    bool dirAsc = ((i & k) == 0);
                    if (g == dirAsc) {
                        s[i] = sj; s[ixj] = si;
                        id[i] = ij; id[ixj] = ii;
                    }
                }
            }
        }
    }
    __syncthreads();
    int* topidx = (int*)(ws + OFF_TOPIDX);
    if (t < KSEL) topidx[t] = id[t];
}

__global__ __launch_bounds__(64) void k_gather(const float* __restrict__ mem, char* ws,
                                               float* __restrict__ out) {
    const int* topidx = (const int*)(ws + OFF_TOPIDX);
    int j = blockIdx.x;
    int idx = topidx[j];
    const float4* src = (const float4*)(mem + (size_t)idx * DIM);
    float4* dst = (float4*)(out + (size_t)j * DIM);
    dst[threadIdx.x] = src[threadIdx.x];
}

extern "C" void kernel_launch(void* const* d_in, const int* in_sizes, int n_in,
                              void* d_out, int out_size, void* d_ws, size_t ws_size,
                              hipStream_t stream) {
    const float* feat = (const float*)d_in[0]; // [1024, 256]
    const float* mem  = (const float*)d_in[1]; // [100000, 256]
    float* out = (float*)d_out;                // [1024, 256]
    char* ws = (char*)d_ws;

    k_init   <<<32, 256, 0, stream>>>(ws);
    k_fsum   <<<16, 256, 0, stream>>>(feat, ws);
    k_scores <<<(NMEM + 3) / 4, 256, 0, stream>>>(mem, ws);
    k_minmax <<<128, 256, 0, stream>>>(ws);
    k_hist   <<<128, 256, 0, stream>>>(ws);
    k_scan   <<<1, 1024, 0, stream>>>(ws);
    k_compact<<<128, 256, 0, stream>>>(ws);
    k_sort   <<<1, 1024, 0, stream>>>(ws);
    k_gather <<<KSEL, 64, 0, stream>>>(mem, ws, out);
}

// Round 2
// 226.180 us; speedup vs baseline: 1.1767x; 1.1767x over previous
//
#include <hip/hip_runtime.h>
#include <stdint.h>

#define NMEM 100000
#define DIM 256
#define BQ 1024
#define KSEL 1024
#define NB 8192
#define CAP 4096

// ---- workspace layout (bytes) ----
#define OFF_SCORES   0                        // NMEM * 8 (double)
#define OFF_FSUM     (NMEM * 8)               // DIM * 8
#define OFF_FSQ      (OFF_FSUM + DIM * 8)     // 8
#define OFF_MINKEY   (OFF_FSQ + 8)            // 8
#define OFF_MAXKEY   (OFF_MINKEY + 8)         // 8
#define OFF_CSCORE   (OFF_MAXKEY + 8)         // CAP * 8
#define OFF_HIST     (OFF_CSCORE + CAP * 8)   // NB * 4
#define OFF_CIDX     (OFF_HIST + NB * 4)      // CAP * 4
#define OFF_COUNTER  (OFF_CIDX + CAP * 4)     // 4
#define OFF_BCUT     (OFF_COUNTER + 4)        // 4
#define OFF_TOPIDX   (OFF_BCUT + 4)           // KSEL * 4
// total ~888 KB

__device__ inline unsigned long long d2k(double d) {
    unsigned long long u = (unsigned long long)__double_as_longlong(d);
    return (u & 0x8000000000000000ull) ? ~u : (u | 0x8000000000000000ull);
}
__device__ inline double k2d(unsigned long long k) {
    unsigned long long u = (k & 0x8000000000000000ull) ? (k ^ 0x8000000000000000ull) : ~k;
    return __longlong_as_double((long long)u);
}
__device__ inline int bucket_of(double s, double vmin, double scale) {
    int b = (int)((s - vmin) * scale);
    if (b < 0) b = 0;
    if (b > NB - 1) b = NB - 1;
    return b;
}

// ---------------- kernels ----------------

__global__ __launch_bounds__(256) void k_init(char* ws) {
    int* hist = (int*)(ws + OFF_HIST);
    double* fsum = (double*)(ws + OFF_FSUM);
    int tid = blockIdx.x * blockDim.x + threadIdx.x;
    int stride = gridDim.x * blockDim.x;
    for (int i = tid; i < NB; i += stride) hist[i] = 0;
    if (tid < DIM) fsum[tid] = 0.0;
    if (tid == 0) {
        *(double*)(ws + OFF_FSQ) = 0.0;
        *(unsigned long long*)(ws + OFF_MINKEY) = ~0ull;
        *(unsigned long long*)(ws + OFF_MAXKEY) = 0ull;
        *(int*)(ws + OFF_COUNTER) = 0;
        *(int*)(ws + OFF_BCUT) = 0;
    }
}

// features [BQ, DIM] -> f_sum[DIM] (double), f_sq (double)
__global__ __launch_bounds__(256) void k_fsum(const float* __restrict__ feat, char* ws) {
    double* fsum = (double*)(ws + OFF_FSUM);
    double* fsq  = (double*)(ws + OFF_FSQ);
    int d = threadIdx.x;          // 0..255 == column
    int r0 = blockIdx.x * 64;     // 16 blocks * 64 rows = 1024
    double s = 0.0, q = 0.0;
    for (int r = r0; r < r0 + 64; ++r) {
        double v = (double)feat[r * DIM + d];
        s += v;
        q += v * v;
    }
    atomicAdd(&fsum[d], s);
    __shared__ double red[256];
    red[d] = q;
    __syncthreads();
    for (int off = 128; off > 0; off >>= 1) {
        if (d < off) red[d] += red[d + off];
        __syncthreads();
    }
    if (d == 0) atomicAdd(fsq, red[0]);
}

// one wave (64 lanes) per memory row; 4 rows per 256-thread block
__global__ __launch_bounds__(256) void k_scores(const float* __restrict__ mem, char* ws) {
    const double* fsum = (const double*)(ws + OFF_FSUM);
    double* scores = (double*)(ws + OFF_SCORES);
    __shared__ double fs[DIM];
    int tid = threadIdx.x;
    fs[tid] = fsum[tid];
    __syncthreads();
    int wave = tid >> 6, lane = tid & 63;
    int row = blockIdx.x * 4 + wave;
    if (row < NMEM) {
        const float4* p = (const float4*)(mem + (size_t)row * DIM);
        float4 v = p[lane];
        const double* f = &fs[lane * 4];
        double msq  = (double)v.x * v.x + (double)v.y * v.y +
                      (double)v.z * v.z + (double)v.w * v.w;
        double cross = (double)v.x * f[0] + (double)v.y * f[1] +
                       (double)v.z * f[2] + (double)v.w * f[3];
        for (int off = 32; off > 0; off >>= 1) {
            msq   += __shfl_down(msq, off);
            cross += __shfl_down(cross, off);
        }
        if (lane == 0) {
            double fsq = *(const double*)(ws + OFF_FSQ);
            scores[row] = 2.0 * cross - (double)BQ * msq - fsq;
        }
    }
}

__global__ __launch_bounds__(256) void k_minmax(char* ws) {
    const double* scores = (const double*)(ws + OFF_SCORES);
    unsigned long long lmin = ~0ull, lmax = 0ull;
    int tid = blockIdx.x * blockDim.x + threadIdx.x;
    int stride = gridDim.x * blockDim.x;
    for (int i = tid; i < NMEM; i += stride) {
        unsigned long long k = d2k(scores[i]);
        if (k < lmin) lmin = k;
        if (k > lmax) lmax = k;
    }
    __shared__ unsigned long long smin[256], smax[256];
    int t = threadIdx.x;
    smin[t] = lmin; smax[t] = lmax;
    __syncthreads();
    for (int off = 128; off > 0; off >>= 1) {
        if (t < off) {
            if (smin[t + off] < smin[t]) smin[t] = smin[t + off];
            if (smax[t + off] > smax[t]) smax[t] = smax[t + off];
        }
        __syncthreads();
    }
    if (t == 0) {
        atomicMin((unsigned long long*)(ws + OFF_MINKEY), smin[0]);
        atomicMax((unsigned long long*)(ws + OFF_MAXKEY), smax[0]);
    }
}

__global__ __launch_bounds__(256) void k_hist(char* ws) {
    const double* scores = (const double*)(ws + OFF_SCORES);
    int* hist = (int*)(ws + OFF_HIST);
    double vmin = k2d(*(unsigned long long*)(ws + OFF_MINKEY));
    double vmax = k2d(*(unsigned long long*)(ws + OFF_MAXKEY));
    double scale = (vmax > vmin) ? (double)NB / (vmax - vmin) : 0.0;
    int tid = blockIdx.x * blockDim.x + threadIdx.x;
    int stride = gridDim.x * blockDim.x;
    for (int i = tid; i < NMEM; i += stride) {
        atomicAdd(&hist[bucket_of(scores[i], vmin, scale)], 1);
    }
}

// find largest b_cut s.t. count(bucket >= b_cut) >= KSEL
__global__ __launch_bounds__(1024) void k_scan(char* ws) {
    const int* hist = (const int*)(ws + OFF_HIST);
    __shared__ int h[NB];     // 32 KB
    __shared__ int suf[1024]; // 4 KB
    int t = threadIdx.x;
    for (int i = t; i < NB; i += 1024) h[i] = hist[i];
    __syncthreads();
    int cs = 0;
    for (int j = 0; j < 8; ++j) cs += h[t * 8 + j];
    suf[t] = cs;
    __syncthreads();
    for (int off = 1; off < 1024; off <<= 1) {
        int v = suf[t] + ((t + off < 1024) ? suf[t + off] : 0);
        __syncthreads();
        suf[t] = v;
        __syncthreads();
    }
    int nxt = (t < 1023) ? suf[t + 1] : 0;
    if (suf[t] >= KSEL && nxt < KSEL) {
        int cum = nxt;
        int bcut = t * 8;
        for (int b = t * 8 + 7; b >= t * 8; --b) {
            cum += h[b];
            if (cum >= KSEL) { bcut = b; break; }
        }
        *(int*)(ws + OFF_BCUT) = bcut;
    }
}

__global__ __launch_bounds__(256) void k_compact(char* ws) {
    const double* scores = (const double*)(ws + OFF_SCORES);
    double vmin = k2d(*(unsigned long long*)(ws + OFF_MINKEY));
    double vmax = k2d(*(unsigned long long*)(ws + OFF_MAXKEY));
    double scale = (vmax > vmin) ? (double)NB / (vmax - vmin) : 0.0;
    int bcut = *(const int*)(ws + OFF_BCUT);
    int* counter = (int*)(ws + OFF_COUNTER);
    double* cs = (double*)(ws + OFF_CSCORE);
    int* ci = (int*)(ws + OFF_CIDX);
    int tid = blockIdx.x * blockDim.x + threadIdx.x;
    int stride = gridDim.x * blockDim.x;
    for (int i = tid; i < NMEM; i += stride) {
        double s = scores[i];
        if (bucket_of(s, vmin, scale) >= bcut) {
            int p = atomicAdd(counter, 1);
            if (p < CAP) { cs[p] = s; ci[p] = i; }
        }
    }
}

// rank-based selection: each thread ranks one candidate against all others.
// rank = #(s_j > s_t) + #(s_j == s_t && id_j < id_t)  -> matches top_k stability.
// Writes topidx[rank] = idx for rank < KSEL. Replaces the bitonic sort.
__global__ __launch_bounds__(256) void k_rank(char* ws) {
    int n = *(const int*)(ws + OFF_COUNTER);
    if (n > CAP) n = CAP;
    const double* cs = (const double*)(ws + OFF_CSCORE);
    const int* ci = (const int*)(ws + OFF_CIDX);
    int* topidx = (int*)(ws + OFF_TOPIDX);
    __shared__ double s[CAP]; // 32 KB
    __shared__ int id[CAP];   // 16 KB
    for (int i = threadIdx.x; i < n; i += 256) { s[i] = cs[i]; id[i] = ci[i]; }
    __syncthreads();
    int t = blockIdx.x * 256 + threadIdx.x;
    if (t < n) {
        double st = s[t];
        int it = id[t];
        int r = 0;
        for (int j = 0; j < n; ++j) {
            double sj = s[j];   // broadcast read: all lanes same address
            int ij = id[j];
            r += (int)((sj > st) | ((sj == st) & (ij < it)));
        }
        if (r < KSEL) topidx[r] = it;
    }
}

__global__ __launch_bounds__(64) void k_gather(const float* __restrict__ mem, char* ws,
                                               float* __restrict__ out) {
    const int* topidx = (const int*)(ws + OFF_TOPIDX);
    int j = blockIdx.x;
    int idx = topidx[j];
    const float4* src = (const float4*)(mem + (size_t)idx * DIM);
    float4* dst = (float4*)(out + (size_t)j * DIM);
    dst[threadIdx.x] = src[threadIdx.x];
}

extern "C" void kernel_launch(void* const* d_in, const int* in_sizes, int n_in,
                              void* d_out, int out_size, void* d_ws, size_t ws_size,
                              hipStream_t stream) {
    const float* feat = (const float*)d_in[0]; // [1024, 256]
    const float* mem  = (const float*)d_in[1]; // [100000, 256]
    float* out = (float*)d_out;                // [1024, 256]
    char* ws = (char*)d_ws;

    k_init   <<<32, 256, 0, stream>>>(ws);
    k_fsum   <<<16, 256, 0, stream>>>(feat, ws);
    k_scores <<<(NMEM + 3) / 4, 256, 0, stream>>>(mem, ws);
    k_minmax <<<128, 256, 0, stream>>>(ws);
    k_hist   <<<128, 256, 0, stream>>>(ws);
    k_scan   <<<1, 1024, 0, stream>>>(ws);
    k_compact<<<128, 256, 0, stream>>>(ws);
    k_rank   <<<CAP / 256, 256, 0, stream>>>(ws);
    k_gather <<<KSEL, 64, 0, stream>>>(mem, ws, out);
}